// Round 2
// baseline (180.809 us; speedup 1.0000x reference)
//
#include <hip/hip_runtime.h>

// AI4Burgers: Lu = 0.5*conv3x3(u,w1) - u_vel*conv3x3(u,w2) - u_vel*conv3x3(u,w3)
// replicate padding, B=16, H=W=1024. fp32 in / fp32 out (Round-1 NaN proved the
// data is float32, not bf16: reading floats as bf16 shorts yields NaN patterns).
//
// Memory-bound stencil -> per-thread register sliding window. Each thread owns
// a 4-pixel strip (one float4 load per row) and walks RPB rows, loading ONE new
// u row per output row. u halo factor (RPB+2)/RPB = 1.25.
// jax.lax.conv_general_dilated does NOT flip kernels (cross-correlation):
//   out[y][x] = sum_{r,k} w[r][k] * u[y+r-1][x+k-1]  (clamped / replicate pad)

#define HH 1024
#define WW 1024
#define RPB 8            // output rows per block
#define PPT 4            // pixels per thread (one float4)
#define TPB (WW / PPT)   // 256 threads

__global__ __launch_bounds__(TPB) void burgers_stencil(
    const float* __restrict__ u,
    const float* __restrict__ uvel,
    const float* __restrict__ w1,
    const float* __restrict__ w2,
    const float* __restrict__ w3,
    float* __restrict__ out,
    int rowBlocks)
{
    const int tid = threadIdx.x;
    const int b   = blockIdx.x / rowBlocks;
    const int y0  = (blockIdx.x % rowBlocks) * RPB;
    const int x0  = tid * PPT;

    // Fold w2+w3: Lu = 0.5*c1 - vel*(c2+c3)
    float W1[9], W23[9];
#pragma unroll
    for (int i = 0; i < 9; ++i) {
        W1[i]  = w1[i];
        W23[i] = w2[i] + w3[i];
    }

    const size_t img = (size_t)b * HH * WW;
    const float* ub = u + img;

    // Sliding window: 3 rows x 6 cols (x0-1 .. x0+4) in registers.
    float win[3][PPT + 2];

    auto loadrow = [&](int yr, float* dst) {
        yr = yr < 0 ? 0 : (yr > HH - 1 ? HH - 1 : yr);   // replicate pad (rows)
        const float* row = ub + (size_t)yr * WW;
        const float4 v = *(const float4*)(row + x0);     // 16B coalesced
        dst[1] = v.x; dst[2] = v.y; dst[3] = v.z; dst[4] = v.w;
        // replicate pad (cols) at image edges, else scalar neighbor (L1-hot:
        // the line was fetched by the adjacent lane's vector load)
        dst[0] = (x0 == 0)        ? v.x : row[x0 - 1];
        dst[5] = (x0 + PPT == WW) ? v.w : row[x0 + PPT];
    };

    loadrow(y0 - 1, win[0]);
    loadrow(y0,     win[1]);

    for (int r = 0; r < RPB; ++r) {
        const int y = y0 + r;
        loadrow(y + 1, win[2]);

        const float4 vv = *(const float4*)(uvel + img + (size_t)y * WW + x0);
        const float vel[PPT] = {vv.x, vv.y, vv.z, vv.w};

        float o[PPT];
#pragma unroll
        for (int j = 0; j < PPT; ++j) {
            float c1 = 0.f, c23 = 0.f;
#pragma unroll
            for (int rr = 0; rr < 3; ++rr) {
#pragma unroll
                for (int k = 0; k < 3; ++k) {
                    const float a = win[rr][j + k];
                    c1  = fmaf(W1[rr*3 + k],  a, c1);
                    c23 = fmaf(W23[rr*3 + k], a, c23);
                }
            }
            o[j] = 0.5f * c1 - vel[j] * c23;
        }
        float4 ov; ov.x = o[0]; ov.y = o[1]; ov.z = o[2]; ov.w = o[3];
        *(float4*)(out + img + (size_t)y * WW + x0) = ov;

        // slide window down one row
#pragma unroll
        for (int k = 0; k < PPT + 2; ++k) {
            win[0][k] = win[1][k];
            win[1][k] = win[2][k];
        }
    }
}

extern "C" void kernel_launch(void* const* d_in, const int* in_sizes, int n_in,
                              void* d_out, int out_size, void* d_ws, size_t ws_size,
                              hipStream_t stream) {
    const float* u    = (const float*)d_in[0];
    const float* uvel = (const float*)d_in[1];
    const float* w1   = (const float*)d_in[2];
    const float* w2   = (const float*)d_in[3];
    const float* w3   = (const float*)d_in[4];
    float* out        = (float*)d_out;

    const int B = in_sizes[0] / (HH * WW);      // 16
    const int rowBlocks = HH / RPB;             // 128
    dim3 grid(B * rowBlocks);                   // 2048 blocks
    dim3 block(TPB);                            // 256 threads, 4 waves
    burgers_stencil<<<grid, block, 0, stream>>>(u, uvel, w1, w2, w3, out, rowBlocks);
}

// Round 3
// 179.547 us; speedup vs baseline: 1.0070x; 1.0070x over previous
//
#include <hip/hip_runtime.h>

// AI4Burgers: Lu = 0.5*conv3x3(u,w1) - u_vel*conv3x3(u,w2) - u_vel*conv3x3(u,w3)
// replicate pad, B=16, H=W=1024, fp32. R2 was latency-bound (VALU 8%, HBM 25%):
// every row iteration waited vmcnt(0) on its own loads. Fix: explicit 1-deep
// software pipeline (issue row r+1 u/uvel/edge loads before consuming row r),
// full unroll so the window rotation is register renaming, and __shfl for the
// horizontal halo (neighbor pixels live in adjacent lanes' registers) so the
// dependent chain has no scalar gather except 2 wave-boundary lanes.

#define HH 1024
#define WW 1024
#define RPB 8            // output rows per block
#define PPT 4            // pixels per thread (one float4)
#define TPB (WW / PPT)   // 256 threads = 4 waves, each wave owns 256 contiguous px

__device__ __forceinline__ float rfl(float x) {
    union { float f; int i; } c; c.f = x;
    c.i = __builtin_amdgcn_readfirstlane(c.i);   // force wave-uniform -> SGPR
    return c.f;
}

struct Row { float4 v; float el, er; };          // vector strip + edge scalars

__global__ __launch_bounds__(TPB, 8) void burgers_stencil(
    const float* __restrict__ u,
    const float* __restrict__ uvel,
    const float* __restrict__ w1,
    const float* __restrict__ w2,
    const float* __restrict__ w3,
    float* __restrict__ out,
    int rowBlocks)
{
    const int tid  = threadIdx.x;
    const int lane = tid & 63;
    const int b    = blockIdx.x / rowBlocks;
    const int y0   = (blockIdx.x % rowBlocks) * RPB;
    const int x0   = tid * PPT;

    // Weights in SGPRs (wave-uniform) — frees ~18 VGPRs; v_fma takes 1 SGPR src.
    float W1[9], W23[9];
#pragma unroll
    for (int i = 0; i < 9; ++i) {
        W1[i]  = rfl(w1[i]);
        W23[i] = rfl(w2[i] + w3[i]);             // fold: Lu = 0.5*c1 - vel*(c2+c3)
    }

    const size_t img = (size_t)b * HH * WW;
    const float* ub  = u + img;

    // Issue phase: vector load + (rare) wave-boundary edge scalars. No waits here.
    auto issue_u = [&](int yr) -> Row {
        yr = yr < 0 ? 0 : (yr > HH - 1 ? HH - 1 : yr);   // replicate pad rows
        const float* row = ub + (size_t)yr * WW;
        Row r;
        r.v  = *(const float4*)(row + x0);
        r.el = 0.f; r.er = 0.f;
        if (lane == 0  && x0 != 0)        r.el = row[x0 - 1];      // masked, L2-hot
        if (lane == 63 && x0 + PPT != WW) r.er = row[x0 + PPT];
        return r;
    };

    // Consume phase: shfl horizontal halo from adjacent lanes, fix wave edges.
    auto expand = [&](const Row& r, float* dst) {
        const float4 v = r.v;
        dst[1] = v.x; dst[2] = v.y; dst[3] = v.z; dst[4] = v.w;
        float left  = __shfl_up(v.w, 1);
        float right = __shfl_down(v.x, 1);
        if (lane == 0)  left  = (x0 == 0)        ? v.x : r.el;     // replicate pad cols
        if (lane == 63) right = (x0 + PPT == WW) ? v.w : r.er;
        dst[0] = left; dst[5] = right;
    };

    // Prime the pipeline: rows y0-1, y0 consumed now; row y0+1 and uvel(y0) in flight.
    Row r0 = issue_u(y0 - 1);
    Row r1 = issue_u(y0);
    Row pu = issue_u(y0 + 1);
    float4 pv = *(const float4*)(uvel + img + (size_t)y0 * WW + x0);

    float win[3][PPT + 2];
    expand(r0, win[0]);
    expand(r1, win[1]);

#pragma unroll
    for (int r = 0; r < RPB; ++r) {
        const int y = y0 + r;

        // Issue next iteration's loads BEFORE consuming this one's (1-iter slack).
        Row nu; float4 nv;
        if (r < RPB - 1) {
            nu = issue_u(y + 2);
            nv = *(const float4*)(uvel + img + (size_t)(y + 1) * WW + x0);
        }

        expand(pu, win[2]);                       // waits on loads issued last iter
        const float vel[PPT] = {pv.x, pv.y, pv.z, pv.w};

        float o[PPT];
#pragma unroll
        for (int j = 0; j < PPT; ++j) {
            float c1 = 0.f, c23 = 0.f;
#pragma unroll
            for (int rr = 0; rr < 3; ++rr) {
#pragma unroll
                for (int k = 0; k < 3; ++k) {
                    const float a = win[rr][j + k];
                    c1  = fmaf(W1[rr*3 + k],  a, c1);
                    c23 = fmaf(W23[rr*3 + k], a, c23);
                }
            }
            o[j] = 0.5f * c1 - vel[j] * c23;
        }
        float4 ov; ov.x = o[0]; ov.y = o[1]; ov.z = o[2]; ov.w = o[3];
        *(float4*)(out + img + (size_t)y * WW + x0) = ov;

        // Rotate window (register renaming under full unroll).
#pragma unroll
        for (int k = 0; k < PPT + 2; ++k) {
            win[0][k] = win[1][k];
            win[1][k] = win[2][k];
        }
        if (r < RPB - 1) { pu = nu; pv = nv; }
    }
}

extern "C" void kernel_launch(void* const* d_in, const int* in_sizes, int n_in,
                              void* d_out, int out_size, void* d_ws, size_t ws_size,
                              hipStream_t stream) {
    const float* u    = (const float*)d_in[0];
    const float* uvel = (const float*)d_in[1];
    const float* w1   = (const float*)d_in[2];
    const float* w2   = (const float*)d_in[3];
    const float* w3   = (const float*)d_in[4];
    float* out        = (float*)d_out;

    const int B = in_sizes[0] / (HH * WW);      // 16
    const int rowBlocks = HH / RPB;             // 128
    dim3 grid(B * rowBlocks);                   // 2048 blocks = 8/CU resident
    dim3 block(TPB);                            // 256 threads, 4 waves
    burgers_stencil<<<grid, block, 0, stream>>>(u, uvel, w1, w2, w3, out, rowBlocks);
}

// Round 4
// 179.025 us; speedup vs baseline: 1.0100x; 1.0029x over previous
//
#include <hip/hip_runtime.h>

// AI4Burgers: Lu = 0.5*conv3x3(u,w1) - u_vel*conv3x3(u,w2) - u_vel*conv3x3(u,w3)
// replicate pad, B=16, H=W=1024, fp32.
//
// R3 lesson: __launch_bounds__(256,8) forced VGPR=32 -> compiler sank all loads
// to their uses, destroying the pipeline (VALU 10%, HBM 27%, latency-bound).
// R4: burst-load block form. Each thread owns a 4x4 tile; ALL loads (6 u-row
// float4 + 12 clamped halo scalars + 4 uvel float4 = 22 VMEM) issue up front
// with no loop-carried deps, then compute, then store. Clamped scalar halo
// loads give replicate padding branch-free (clamp IS the pad) and avoid
// __shfl's lgkmcnt serialization. No launch-bounds cap: registers buy MLP.

#define HH 1024
#define WW 1024
#define RPB 4            // output rows per thread/block tile
#define PPT 4            // pixels per thread (one float4)
#define TPB (WW / PPT)   // 256 threads

__device__ __forceinline__ float rfl(float x) {
    union { float f; int i; } c; c.f = x;
    c.i = __builtin_amdgcn_readfirstlane(c.i);   // wave-uniform -> SGPR
    return c.f;
}

__global__ __launch_bounds__(TPB) void burgers_stencil(
    const float* __restrict__ u,
    const float* __restrict__ uvel,
    const float* __restrict__ w1,
    const float* __restrict__ w2,
    const float* __restrict__ w3,
    float* __restrict__ out,
    int rowBlocks)
{
    const int tid = threadIdx.x;
    const int b   = blockIdx.x / rowBlocks;
    const int y0  = (blockIdx.x % rowBlocks) * RPB;
    const int x0  = tid * PPT;

    const size_t img = (size_t)b * HH * WW;
    const float* ub  = u + img;

    // Horizontal halo columns, clamped = replicate padding for free.
    const int xl = (x0 == 0) ? 0 : x0 - 1;
    const int xr = (x0 + PPT >= WW) ? WW - 1 : x0 + PPT;

    // ---- burst: issue every load, zero inter-load dependence ----
    float4 uv[RPB + 2]; float ul[RPB + 2], ur[RPB + 2];
#pragma unroll
    for (int i = 0; i < RPB + 2; ++i) {
        int yr = y0 - 1 + i;
        yr = yr < 0 ? 0 : (yr > HH - 1 ? HH - 1 : yr);   // replicate pad rows
        const float* row = ub + (size_t)yr * WW;
        uv[i] = *(const float4*)(row + x0);              // 16B coalesced
        ul[i] = row[xl];                                 // L1/L2-hot (neighbor's line)
        ur[i] = row[xr];
    }
    float4 vv[RPB];
#pragma unroll
    for (int r = 0; r < RPB; ++r)
        vv[r] = *(const float4*)(uvel + img + (size_t)(y0 + r) * WW + x0);

    // Weights -> SGPRs. (s_load path; rfl guarantees no VGPR copies.)
    float W1[9], W23[9];
#pragma unroll
    for (int i = 0; i < 9; ++i) {
        W1[i]  = rfl(w1[i]);
        W23[i] = rfl(w2[i] + w3[i]);    // fold: Lu = 0.5*c1 - vel*(c2+c3)
    }

    __builtin_amdgcn_sched_barrier(0);  // keep the load burst above the math

    // ---- compute + store, rows consumed in load order ----
#pragma unroll
    for (int r = 0; r < RPB; ++r) {
        // padded 3x6 window for this output row, straight from registers
        float p[3][PPT + 2];
#pragma unroll
        for (int rr = 0; rr < 3; ++rr) {
            const int i = r + rr;
            p[rr][0] = ul[i];
            p[rr][1] = uv[i].x; p[rr][2] = uv[i].y;
            p[rr][3] = uv[i].z; p[rr][4] = uv[i].w;
            p[rr][5] = ur[i];
        }
        const float vel[PPT] = {vv[r].x, vv[r].y, vv[r].z, vv[r].w};

        float o[PPT];
#pragma unroll
        for (int j = 0; j < PPT; ++j) {
            float c1 = 0.f, c23 = 0.f;
#pragma unroll
            for (int rr = 0; rr < 3; ++rr) {
#pragma unroll
                for (int k = 0; k < 3; ++k) {
                    const float a = p[rr][j + k];
                    c1  = fmaf(W1[rr*3 + k],  a, c1);
                    c23 = fmaf(W23[rr*3 + k], a, c23);
                }
            }
            o[j] = 0.5f * c1 - vel[j] * c23;
        }
        float4 ov; ov.x = o[0]; ov.y = o[1]; ov.z = o[2]; ov.w = o[3];
        *(float4*)(out + img + (size_t)(y0 + r) * WW + x0) = ov;
    }
}

extern "C" void kernel_launch(void* const* d_in, const int* in_sizes, int n_in,
                              void* d_out, int out_size, void* d_ws, size_t ws_size,
                              hipStream_t stream) {
    const float* u    = (const float*)d_in[0];
    const float* uvel = (const float*)d_in[1];
    const float* w1   = (const float*)d_in[2];
    const float* w2   = (const float*)d_in[3];
    const float* w3   = (const float*)d_in[4];
    float* out        = (float*)d_out;

    const int B = in_sizes[0] / (HH * WW);      // 16
    const int rowBlocks = HH / RPB;             // 256
    dim3 grid(B * rowBlocks);                   // 4096 blocks
    dim3 block(TPB);                            // 256 threads, 4 waves
    burgers_stencil<<<grid, block, 0, stream>>>(u, uvel, w1, w2, w3, out, rowBlocks);
}

// Round 5
// 174.522 us; speedup vs baseline: 1.0360x; 1.0258x over previous
//
#include <hip/hip_runtime.h>

// AI4Burgers: Lu = 0.5*conv3x3(u,w1) - u_vel*conv3x3(u,w2) - u_vel*conv3x3(u,w3)
// replicate pad, B=16, H=W=1024, fp32.
//
// R3/R4 lesson: the AMDGPU scheduler sinks register-destined global loads to
// their uses no matter what (VGPR pinned at 32 twice), leaving ~1-deep load
// chains -> latency-bound at 25-31% HBM. Fix: async global->LDS DMA
// (global_load_lds, width 16). No destination VGPR => nothing to sink; all
// row-DMAs issue back-to-back and drain at one __syncthreads() (vmcnt(0)
// before s_barrier). Block covers full 1024-px rows, so the horizontal halo
// is always in LDS: clamped LDS index == replicate padding, no shfl, no
// scalar global gathers. uvel is pointwise -> direct float4 regs, issued
// before the barrier so its latency hides under the DMA drain.

#define HH 1024
#define WW 1024
#define RPB 4                 // output rows per block
#define TPB 256               // 4 waves; wave w owns cols [256w, 256w+256)
#define NROW (RPB + 2)        // u rows staged (halo factor 1.5)

typedef __attribute__((address_space(3))) void       lds_void;
typedef __attribute__((address_space(1))) const void gbl_void;

__device__ __forceinline__ float rfl(float x) {
    union { float f; int i; } c; c.f = x;
    c.i = __builtin_amdgcn_readfirstlane(c.i);   // wave-uniform -> SGPR
    return c.f;
}

__global__ __launch_bounds__(TPB) void burgers_stencil(
    const float* __restrict__ u,
    const float* __restrict__ uvel,
    const float* __restrict__ w1,
    const float* __restrict__ w2,
    const float* __restrict__ w3,
    float* __restrict__ out,
    int rowBlocks)
{
    __shared__ float tile[NROW * WW];            // 24 KiB

    const int tid  = threadIdx.x;
    const int wave = tid >> 6;
    const int lane = tid & 63;
    const int b    = blockIdx.x / rowBlocks;
    const int y0   = (blockIdx.x % rowBlocks) * RPB;
    const int x0   = tid * 4;

    const size_t img = (size_t)b * HH * WW;
    const float* ub  = u + img;

    // ---- async DMA: u rows y0-1 .. y0+RPB -> LDS. No dest VGPRs, un-sinkable.
    // Wave-uniform LDS base + lane*16 (m104/m108 constraint): wave w's 64
    // lanes fill floats [256w .. 256w+255] of row i.
#pragma unroll
    for (int i = 0; i < NROW; ++i) {
        int yr = y0 - 1 + i;
        yr = yr < 0 ? 0 : (yr > HH - 1 ? HH - 1 : yr);       // replicate pad rows
        const float* g = ub + (size_t)yr * WW + wave * 256 + lane * 4;
        __builtin_amdgcn_global_load_lds((gbl_void*)g,
                                         (lds_void*)&tile[i * WW + wave * 256],
                                         16, 0, 0);
    }

    // ---- uvel straight to registers; issued pre-barrier, overlaps DMA drain.
    float4 vv[RPB];
#pragma unroll
    for (int r = 0; r < RPB; ++r)
        vv[r] = *(const float4*)(uvel + img + (size_t)(y0 + r) * WW + x0);

    // ---- weights -> SGPRs (fold w2+w3: Lu = 0.5*c1 - vel*(c2+c3))
    float W1[9], W23[9];
#pragma unroll
    for (int i = 0; i < 9; ++i) {
        W1[i]  = rfl(w1[i]);
        W23[i] = rfl(w2[i] + w3[i]);
    }

    __syncthreads();   // s_waitcnt vmcnt(0) + s_barrier: DMA done, uvel in regs

    // ---- compute from LDS; clamped LDS col index == replicate pad cols
    const int xm1 = (x0 == 0)       ? 0      : x0 - 1;
    const int xp4 = (x0 + 4 >= WW)  ? WW - 1 : x0 + 4;

#pragma unroll
    for (int r = 0; r < RPB; ++r) {
        float p[3][6];
#pragma unroll
        for (int rr = 0; rr < 3; ++rr) {
            const float* row = &tile[(r + rr) * WW];
            const float4 m = *(const float4*)(row + x0);     // ds_read_b128
            p[rr][0] = row[xm1];                             // ds_read_b32
            p[rr][1] = m.x; p[rr][2] = m.y;
            p[rr][3] = m.z; p[rr][4] = m.w;
            p[rr][5] = row[xp4];                             // ds_read_b32
        }
        const float vel[4] = {vv[r].x, vv[r].y, vv[r].z, vv[r].w};

        float o[4];
#pragma unroll
        for (int j = 0; j < 4; ++j) {
            float c1 = 0.f, c23 = 0.f;
#pragma unroll
            for (int rr = 0; rr < 3; ++rr) {
#pragma unroll
                for (int k = 0; k < 3; ++k) {
                    const float a = p[rr][j + k];
                    c1  = fmaf(W1[rr*3 + k],  a, c1);
                    c23 = fmaf(W23[rr*3 + k], a, c23);
                }
            }
            o[j] = 0.5f * c1 - vel[j] * c23;
        }
        float4 ov; ov.x = o[0]; ov.y = o[1]; ov.z = o[2]; ov.w = o[3];
        *(float4*)(out + img + (size_t)(y0 + r) * WW + x0) = ov;
    }
}

extern "C" void kernel_launch(void* const* d_in, const int* in_sizes, int n_in,
                              void* d_out, int out_size, void* d_ws, size_t ws_size,
                              hipStream_t stream) {
    const float* u    = (const float*)d_in[0];
    const float* uvel = (const float*)d_in[1];
    const float* w1   = (const float*)d_in[2];
    const float* w2   = (const float*)d_in[3];
    const float* w3   = (const float*)d_in[4];
    float* out        = (float*)d_out;

    const int B = in_sizes[0] / (HH * WW);      // 16
    const int rowBlocks = HH / RPB;             // 256
    dim3 grid(B * rowBlocks);                   // 4096 blocks, ~16/CU over time
    dim3 block(TPB);                            // 256 threads, 4 waves
    burgers_stencil<<<grid, block, 0, stream>>>(u, uvel, w1, w2, w3, out, rowBlocks);
}